// Round 7
// baseline (375.503 us; speedup 1.0000x reference)
//
#include <hip/hip_runtime.h>
#include <math.h>

typedef __attribute__((ext_vector_type(8))) short short8;
typedef __attribute__((ext_vector_type(16))) float floatx16;

#define NSV 8192
#define MSV 8192
#define CF 96
#define NCLS 20

#define C48 48.08983469629878f     // 1/(0.03*ln2)
#define C96 96.17966939259756f     // 2*C48
#define CEV -2.885390081777927f    // -2/ln2

// ---- workspace byte offsets ----
#define OFF_A0    0u
#define OFF_A1    1572864u
#define OFF_A2    3145728u
#define OFF_B0    4718592u
#define OFF_B1    6291456u
#define OFF_B2    7864320u
#define OFF_RV4   9437184u   // float4[8192]: x = 1/|a| (prep) then b_i (bvec); yzw = ori
#define OFF_CV4   9568256u   // float4[8192]: x = 1/|b|; yzw = al_sur
#define OFF_PROW  9699328u   // float[8192*64] partial row sums
#define OFF_SMENC 11796480u  // u64[8192]
#define OFF_SMIDX 11862016u
#define OFF_WIN   11894784u
#define OFF_CONF  11927552u
#define OFF_FLAG  11960320u

// ---- output float offsets ----
#define O_TRUST 0
#define O_PROB  NSV
#define O_PRE   (O_PROB + NSV*NCLS)
#define O_SM    (O_PRE + NSV)

__device__ __forceinline__ unsigned short bfr(float x) {
  unsigned u = __float_as_uint(x);
  return (unsigned short)((u + 0x7FFFu + ((u >> 16) & 1u)) >> 16);
}
__device__ __forceinline__ float bff(unsigned short h) {
  return __uint_as_float(((unsigned)h) << 16);
}
__device__ __forceinline__ float fexp2(float x) {
  float r; asm("v_exp_f32 %0, %1" : "=v"(r) : "v"(x)); return r;
}

// 4x4 inverse (fp64 Gauss-Jordan) + norms, coord transform, packed structs
__global__ void k_prep(const float* __restrict__ surf, const float* __restrict__ surc,
                       const float* __restrict__ meanf, const float* __restrict__ ori,
                       const float* __restrict__ posses, char* __restrict__ wsb) {
  __shared__ float dsh[12];
  if (threadIdx.x == 0) {
    double m[4][8];
    for (int r = 0; r < 4; ++r)
      for (int c = 0; c < 4; ++c) { m[r][c] = (double)posses[16 + r*4 + c]; m[r][4+c] = (r == c) ? 1.0 : 0.0; }
    for (int col = 0; col < 4; ++col) {
      int piv = col; double best = fabs(m[col][col]);
      for (int r = col+1; r < 4; ++r) { double v = fabs(m[r][col]); if (v > best) { best = v; piv = r; } }
      if (piv != col) for (int c = 0; c < 8; ++c) { double tt = m[col][c]; m[col][c] = m[piv][c]; m[piv][c] = tt; }
      double pv = m[col][col];
      for (int c = 0; c < 8; ++c) m[col][c] /= pv;
      for (int r = 0; r < 4; ++r) if (r != col) {
        double f = m[r][col];
        for (int c = 0; c < 8; ++c) m[r][c] -= f * m[col][c];
      }
    }
    for (int r = 0; r < 3; ++r)
      for (int c = 0; c < 4; ++c) {
        double s = 0.0;
        for (int k = 0; k < 4; ++k) s += m[r][4+k] * (double)posses[k*4 + c];
        dsh[r*4 + c] = (float)s;
      }
  }
  __syncthreads();
  int j = blockIdx.x*256 + threadIdx.x;
  if (j >= NSV) return;
  float d[12];
  #pragma unroll
  for (int q = 0; q < 12; ++q) d[q] = dsh[q];
  float x = surc[j*3+0], y = surc[j*3+1], z = surc[j*3+2];
  float ax = ((x*d[0] + y*d[1]) + z*d[2]) + d[3];
  float ay = ((x*d[4] + y*d[5]) + z*d[6]) + d[7];
  float az = ((x*d[8] + y*d[9]) + z*d[10]) + d[11];
  const float4* f2 = (const float4*)(surf  + (size_t)j*CF);
  const float4* f1 = (const float4*)(meanf + (size_t)j*CF);
  float s2 = 0.f, s1 = 0.f;
  #pragma unroll
  for (int kq = 0; kq < 24; ++kq) {
    float4 v = f2[kq]; s2 += v.x*v.x; s2 += v.y*v.y; s2 += v.z*v.z; s2 += v.w*v.w;
  }
  #pragma unroll
  for (int kq = 0; kq < 24; ++kq) {
    float4 v = f1[kq]; s1 += v.x*v.x; s1 += v.y*v.y; s1 += v.z*v.z; s1 += v.w*v.w;
  }
  float4 cvv; cvv.x = 1.0f/sqrtf(s2); cvv.y = ax; cvv.z = ay; cvv.w = az;
  ((float4*)(wsb + OFF_CV4))[j] = cvv;
  float4 rvv; rvv.x = 1.0f/sqrtf(s1); rvv.y = ori[j*3+0]; rvv.z = ori[j*3+1]; rvv.w = ori[j*3+2];
  ((float4*)(wsb + OFF_RV4))[j] = rvv;
}

// 3-way bf16 split of PRE-SCALED features: A side x 48.09/|a|, B side x 1/|b|.
__global__ void k_split(const float* __restrict__ meanf, const float* __restrict__ surf,
                        char* __restrict__ wsb) {
  const int NT = NSV*CF/4;
  int idx = blockIdx.x*256 + threadIdx.x;
  if (idx >= 2*NT) return;
  int m = idx >= NT;
  int e4 = idx - (m ? NT : 0);
  int base4 = e4 * 4;
  int row = base4 / CF;
  const float* src = m ? surf : meanf;
  float scale;
  if (m) scale = ((const float4*)(wsb + OFF_CV4))[row].x;
  else   scale = ((const float4*)(wsb + OFF_RV4))[row].x * C48;
  unsigned short* d0 = (unsigned short*)(wsb + (m ? OFF_B0 : OFF_A0));
  unsigned short* d1 = (unsigned short*)(wsb + (m ? OFF_B1 : OFF_A1));
  unsigned short* d2 = (unsigned short*)(wsb + (m ? OFF_B2 : OFF_A2));
  float4 v = *(const float4*)(src + base4);
  float xs[4] = {v.x*scale, v.y*scale, v.z*scale, v.w*scale};
  unsigned short h0[4], h1[4], h2[4];
  #pragma unroll
  for (int c = 0; c < 4; ++c) {
    float x = xs[c];
    unsigned short a0 = bfr(x);  float r1 = x - bff(a0);
    unsigned short a1 = bfr(r1); float r2 = r1 - bff(a1);
    h0[c] = a0; h1[c] = a1; h2[c] = bfr(r2);
  }
  *(ushort4*)(d0 + base4) = make_ushort4(h0[0], h0[1], h0[2], h0[3]);
  *(ushort4*)(d1 + base4) = make_ushort4(h1[0], h1[1], h1[2], h1[3]);
  *(ushort4*)(d2 + base4) = make_ushort4(h2[0], h2[1], h2[2], h2[3]);
}

// Heavy GEMM pass: 128x128 tile, 4 waves (2x2), wave tile 64x64 via 2x2 mfma_32x32x16_bf16.
// 3-split operands (6 products). 3 LDS buffers, prefetch depth 2, counted vmcnt(6).
// RACE-FREE placement: stage(kc+2) issued AFTER barrier(kc)+ds_read (all waves'
// reads of the overwritten buffer completed before their barrier(kc) entry).
// PASS 1: rowsums.  PASS 2: per-column argmax of K*b.
template<int PASS>
__global__ __launch_bounds__(256, 2)
void k_gemm(char* __restrict__ wsb) {
  const unsigned short* Sp[6] = {(const unsigned short*)(wsb+OFF_A0),
                                 (const unsigned short*)(wsb+OFF_A1),
                                 (const unsigned short*)(wsb+OFF_A2),
                                 (const unsigned short*)(wsb+OFF_B0),
                                 (const unsigned short*)(wsb+OFF_B1),
                                 (const unsigned short*)(wsb+OFF_B2)};
  const float4* RV  = (const float4*)(wsb + OFF_RV4);
  const float4* CVC = (const float4*)(wsb + OFF_CV4);
  float* PROW = (float*)(wsb + OFF_PROW);
  unsigned long long* SME = (unsigned long long*)(wsb + OFF_SMENC);

  __shared__ char lds[73728];                   // 3 bufs x 6 slots x 4096 B
  __shared__ unsigned long long redbuf[2][128];

  int t = threadIdx.x, lane = t & 63, wid = t >> 6;
  int wr = wid >> 1, wc = wid & 1, l31 = lane & 31, hi = lane >> 5;
  // 2D XCD chunking: XCD (xr,xc) owns 16 bi x 32 bj -> L2-resident panels
  int flat = blockIdx.y*64 + blockIdx.x;
  int xcd = flat & 7, q = flat >> 3;
  int xr = xcd >> 1, xc = xcd & 1;
  int bi = xr*16 + (q & 15), bj = xc*32 + (q >> 4);
  int I0 = bi*128, J0 = bj*128;

  // pre-swizzled global source (linear LDS dest, swizzled read)
  int d16 = t * 16;
  int sl = d16 ^ (((d16 >> 7) & 7) << 4);
  int srow = sl >> 5;
  int shalf = (sl >> 4) & 1;

  auto stage = [&](int buf, int kc) {
    #pragma unroll
    for (int s = 0; s < 6; ++s) {
      int P0 = (s < 3) ? I0 : J0;
      const unsigned short* gp = Sp[s] + ((size_t)(P0 + srow)*CF + kc*16 + shalf*8);
      char* lp = lds + buf*24576 + s*4096 + wid*1024;
      __builtin_amdgcn_global_load_lds((const __attribute__((address_space(1))) void*)gp,
                                       (__attribute__((address_space(3))) void*)lp, 16, 0, 0);
    }
  };

  floatx16 acc[2][2];
  #pragma unroll
  for (int ti = 0; ti < 2; ++ti)
    #pragma unroll
    for (int tj = 0; tj < 2; ++tj)
      #pragma unroll
      for (int e = 0; e < 16; ++e) acc[ti][tj][e] = 0.f;

  int laA[2], laB[2];
  #pragma unroll
  for (int ti = 0; ti < 2; ++ti) {
    int a = (wr*64 + ti*32 + l31)*32 + hi*16;
    laA[ti] = a ^ (((a >> 7) & 7) << 4);
    int b = (wc*64 + ti*32 + l31)*32 + hi*16;
    laB[ti] = b ^ (((b >> 7) & 7) << 4);
  }

  stage(0, 0);
  stage(1, 1);

  #pragma unroll
  for (int kc = 0; kc < 6; ++kc) {
    int cur = kc % 3;
    if (kc < 5) {
      asm volatile("s_waitcnt vmcnt(6)" ::: "memory");   // stage(kc) landed; stage(kc+1) in flight
    } else {
      asm volatile("s_waitcnt vmcnt(0)" ::: "memory");
    }
    __builtin_amdgcn_s_barrier();
    asm volatile("" ::: "memory");
    short8 fa[3][2], fb[3][2];
    #pragma unroll
    for (int sp = 0; sp < 3; ++sp)
      #pragma unroll
      for (int ti = 0; ti < 2; ++ti) {
        fa[sp][ti] = *(const short8*)(lds + cur*24576 + sp*4096 + laA[ti]);
        fb[sp][ti] = *(const short8*)(lds + cur*24576 + (3+sp)*4096 + laB[ti]);
      }
    if (kc < 4) stage((kc + 2) % 3, kc + 2);             // safe: after barrier(kc)
    #pragma unroll
    for (int ti = 0; ti < 2; ++ti)
      #pragma unroll
      for (int tj = 0; tj < 2; ++tj) {
        acc[ti][tj] = __builtin_amdgcn_mfma_f32_32x32x16_bf16(fa[0][ti], fb[0][tj], acc[ti][tj], 0, 0, 0);
        acc[ti][tj] = __builtin_amdgcn_mfma_f32_32x32x16_bf16(fa[0][ti], fb[1][tj], acc[ti][tj], 0, 0, 0);
        acc[ti][tj] = __builtin_amdgcn_mfma_f32_32x32x16_bf16(fa[1][ti], fb[0][tj], acc[ti][tj], 0, 0, 0);
        acc[ti][tj] = __builtin_amdgcn_mfma_f32_32x32x16_bf16(fa[1][ti], fb[1][tj], acc[ti][tj], 0, 0, 0);
        acc[ti][tj] = __builtin_amdgcn_mfma_f32_32x32x16_bf16(fa[0][ti], fb[2][tj], acc[ti][tj], 0, 0, 0);
        acc[ti][tj] = __builtin_amdgcn_mfma_f32_32x32x16_bf16(fa[2][ti], fb[0][tj], acc[ti][tj], 0, 0, 0);
      }
  }

  // ---- epilogue ----
  float4 cv[2];
  #pragma unroll
  for (int tj = 0; tj < 2; ++tj) cv[tj] = CVC[J0 + wc*64 + tj*32 + l31];

  if (PASS == 1) {
    float* rowred = (float*)redbuf;   // [2][128] floats
    #pragma unroll
    for (int ti = 0; ti < 2; ++ti) {
      #pragma unroll
      for (int r = 0; r < 16; ++r) {
        int lr = wr*64 + ti*32 + (r & 3) + 8*(r >> 2) + 4*hi;
        int row = I0 + lr;
        float4 rv = RV[row];
        float rowp = 0.f;
        #pragma unroll
        for (int tj = 0; tj < 2; ++tj) {
          float dotv = acc[ti][tj][r];                  // = 48.09 * cos
          float dx = rv.y - cv[tj].y, dy = rv.z - cv[tj].z, dz = rv.w - cv[tj].w;
          float s3 = fmaf(dz, dz, fmaf(dy, dy, dx*dx));
          float ev = fexp2(s3 * CEV);                   // exp(-2*s3)
          float kv = fexp2(fmaf(ev, C48, dotv - C96));
          kv = (s3 < 25.0f) ? kv : 0.0f;
          rowp += kv;
        }
        rowp += __shfl_xor(rowp, 1);
        rowp += __shfl_xor(rowp, 2);
        rowp += __shfl_xor(rowp, 4);
        rowp += __shfl_xor(rowp, 8);
        rowp += __shfl_xor(rowp, 16);
        if (l31 == 0) rowred[wc*128 + lr] = rowp;
      }
    }
    __syncthreads();
    if (t < 128) PROW[(size_t)(I0 + t)*64 + bj] = rowred[t] + rowred[128 + t];
  } else {
    unsigned long long benc[2] = {0ull, 0ull};
    #pragma unroll
    for (int ti = 0; ti < 2; ++ti) {
      #pragma unroll
      for (int r = 0; r < 16; ++r) {
        int lr = wr*64 + ti*32 + (r & 3) + 8*(r >> 2) + 4*hi;
        int row = I0 + lr;
        float4 rv = RV[row];                            // rv.x = b_i
        unsigned rinv = 0xFFFFFFFFu - (unsigned)row;
        #pragma unroll
        for (int tj = 0; tj < 2; ++tj) {
          float dotv = acc[ti][tj][r];
          float dx = rv.y - cv[tj].y, dy = rv.z - cv[tj].z, dz = rv.w - cv[tj].w;
          float s3 = fmaf(dz, dz, fmaf(dy, dy, dx*dx));
          float ev = fexp2(s3 * CEV);
          float kv = fexp2(fmaf(ev, C48, dotv - C96));
          kv = (s3 < 25.0f) ? kv : 0.0f;
          float val = kv * rv.x;
          unsigned long long e = ((unsigned long long)__float_as_uint(val) << 32)
                               | (unsigned long long)rinv;
          benc[tj] = (e > benc[tj]) ? e : benc[tj];
        }
      }
    }
    #pragma unroll
    for (int tj = 0; tj < 2; ++tj) {
      unsigned long long o = __shfl_xor(benc[tj], 32);
      if (o > benc[tj]) benc[tj] = o;
      if (hi == 0) redbuf[wr][wc*64 + tj*32 + l31] = benc[tj];
    }
    __syncthreads();
    if (t < 128) {
      unsigned long long e0 = redbuf[0][t], e1 = redbuf[1][t];
      atomicMax(SME + (J0 + t), e0 > e1 ? e0 : e1);
    }
  }
}

// reduce partials -> b_i into RV4.x; init winner/flag/smenc
__global__ void k_bvec(char* __restrict__ wsb) {
  int i = blockIdx.x*256 + threadIdx.x;
  if (i >= NSV) return;
  const float* p = (const float*)(wsb + OFF_PROW) + (size_t)i*64;
  float s = 0.f;
  #pragma unroll
  for (int q = 0; q < 64; ++q) s += p[q];
  float b = 0x1p-13f / (s * 0x1p-13f + 1e-16f);
  ((float*)(wsb + OFF_RV4))[(size_t)i*4] = b;
  ((int*)(wsb + OFF_WIN))[i] = -1;
  ((unsigned long long*)(wsb + OFF_SMENC))[i] = 0ull;
  if (i == 0) *((int*)(wsb + OFF_FLAG)) = 0;
}

__global__ void k_softmax(const float* __restrict__ svp, float* __restrict__ out) {
  int i = blockIdx.x*256 + threadIdx.x;
  if (i >= NSV) return;
  const float* x = svp + (size_t)i*NCLS;
  float mx = x[0];
  for (int c = 1; c < NCLS; ++c) mx = fmaxf(mx, x[c]);
  float e[NCLS]; float s = 0.f;
  for (int c = 0; c < NCLS; ++c) { e[c] = expf(x[c] - mx); s += e[c]; }
  float* p = out + O_PROB + (size_t)i*NCLS;
  for (int c = 0; c < NCLS; ++c) p[c] = e[c]/s;
}

__global__ void k_conf(const int* __restrict__ gt, char* __restrict__ wsb, float* __restrict__ out) {
  int j = blockIdx.x*256 + threadIdx.x;
  if (j >= MSV) return;
  unsigned long long enc = ((const unsigned long long*)(wsb + OFF_SMENC))[j];
  int sm = (int)(0xFFFFFFFFu - (unsigned)(enc & 0xFFFFFFFFull));
  ((int*)(wsb + OFF_SMIDX))[j] = sm;
  out[O_SM + j] = (float)sm;
  float c = out[O_PROB + (size_t)sm*NCLS + gt[j]];
  ((float*)(wsb + OFF_CONF))[j] = c;
  unsigned long long m = __ballot(c > 0.1f);
  if ((threadIdx.x & 63) == 0 && m) atomicOr((int*)(wsb + OFF_FLAG), 1);
}

__global__ void k_winner(char* __restrict__ wsb) {
  int j = blockIdx.x*256 + threadIdx.x;
  if (j >= MSV) return;
  float c = ((const float*)(wsb + OFF_CONF))[j];
  int f = *((const int*)(wsb + OFF_FLAG));
  bool tm = f ? (c > 0.1f) : (c > 0.0f);
  if (tm) atomicMax(((int*)(wsb + OFF_WIN)) + ((const int*)(wsb + OFF_SMIDX))[j], j);
}

__global__ void k_final(const int* __restrict__ gt, float* __restrict__ out, const char* __restrict__ wsb) {
  int i = blockIdx.x*256 + threadIdx.x;
  if (i >= NSV) return;
  int w = ((const int*)(wsb + OFF_WIN))[i];
  float* row = out + O_PROB + (size_t)i*NCLS;
  if (w >= 0) {
    int g = gt[w];
    for (int c = 0; c < NCLS; ++c) row[c] = (c == g) ? 1.f : 0.f;
  }
  out[O_TRUST + i] = (w >= 0) ? 1.f : 0.f;
  float mx = row[0]; int pi = 0;
  for (int c = 1; c < NCLS; ++c) { float v = row[c]; if (v > mx) { mx = v; pi = c; } }
  out[O_PRE + i] = (float)pi;
}

extern "C" void kernel_launch(void* const* d_in, const int* in_sizes, int n_in,
                              void* d_out, int out_size, void* d_ws, size_t ws_size,
                              hipStream_t stream) {
  const float* surf  = (const float*)d_in[0];
  const float* surc  = (const float*)d_in[1];
  const int*   gt    = (const int*)d_in[2];
  const float* svp   = (const float*)d_in[3];
  const float* meanf = (const float*)d_in[4];
  const float* ori   = (const float*)d_in[5];
  const float* poss  = (const float*)d_in[6];
  float* out = (float*)d_out;
  char* wsb = (char*)d_ws;

  k_prep<<<NSV/256, 256, 0, stream>>>(surf, surc, meanf, ori, poss, wsb);
  k_split<<<1536, 256, 0, stream>>>(meanf, surf, wsb);
  k_gemm<1><<<dim3(64, 64), 256, 0, stream>>>(wsb);
  k_bvec<<<NSV/256, 256, 0, stream>>>(wsb);
  k_gemm<2><<<dim3(64, 64), 256, 0, stream>>>(wsb);
  k_softmax<<<NSV/256, 256, 0, stream>>>(svp, out);
  k_conf<<<MSV/256, 256, 0, stream>>>(gt, wsb, out);
  k_winner<<<MSV/256, 256, 0, stream>>>(wsb);
  k_final<<<NSV/256, 256, 0, stream>>>(gt, out, wsb);
}

// Round 8
// 294.162 us; speedup vs baseline: 1.2765x; 1.2765x over previous
//
#include <hip/hip_runtime.h>
#include <math.h>

typedef __attribute__((ext_vector_type(8))) short short8;
typedef __attribute__((ext_vector_type(16))) float floatx16;

#define NSV 8192
#define MSV 8192
#define CF 96
#define NCLS 20

#define C48 48.08983469629878f     // 1/(0.03*ln2)
#define C96 96.17966939259756f     // 2*C48
#define CEV -2.885390081777927f    // -2/ln2

// ---- workspace byte offsets ----
// A/B splits stored FRAGMENT-PACKED: within split s, byte offset
//   ((g*6 + kc) << 10) + lane*16,  g = rowgroup (32 rows), kc = k-chunk (16 k),
//   lane = (k_half<<5) | (row&31); each 16B = 8 bf16 of one row's k-half.
#define OFF_A0    0u
#define OFF_A1    1572864u
#define OFF_A2    3145728u
#define OFF_B0    4718592u
#define OFF_B1    6291456u
#define OFF_B2    7864320u
#define OFF_RV4   9437184u   // float4[8192]: x = 1/|a| (prep) then b_i (bvec); yzw = ori
#define OFF_CV4   9568256u   // float4[8192]: x = 1/|b|; yzw = al_sur
#define OFF_PROW  9699328u   // float[8192*64] partial row sums
#define OFF_SMENC 11796480u  // u64[8192]
#define OFF_SMIDX 11862016u
#define OFF_WIN   11894784u
#define OFF_CONF  11927552u
#define OFF_FLAG  11960320u

// ---- output float offsets ----
#define O_TRUST 0
#define O_PROB  NSV
#define O_PRE   (O_PROB + NSV*NCLS)
#define O_SM    (O_PRE + NSV)

__device__ __forceinline__ unsigned short bfr(float x) {
  unsigned u = __float_as_uint(x);
  return (unsigned short)((u + 0x7FFFu + ((u >> 16) & 1u)) >> 16);
}
__device__ __forceinline__ float bff(unsigned short h) {
  return __uint_as_float(((unsigned)h) << 16);
}
__device__ __forceinline__ float fexp2(float x) {
  float r; asm("v_exp_f32 %0, %1" : "=v"(r) : "v"(x)); return r;
}

// 4x4 inverse (fp64 Gauss-Jordan) + norms, coord transform, packed structs
__global__ void k_prep(const float* __restrict__ surf, const float* __restrict__ surc,
                       const float* __restrict__ meanf, const float* __restrict__ ori,
                       const float* __restrict__ posses, char* __restrict__ wsb) {
  __shared__ float dsh[12];
  if (threadIdx.x == 0) {
    double m[4][8];
    for (int r = 0; r < 4; ++r)
      for (int c = 0; c < 4; ++c) { m[r][c] = (double)posses[16 + r*4 + c]; m[r][4+c] = (r == c) ? 1.0 : 0.0; }
    for (int col = 0; col < 4; ++col) {
      int piv = col; double best = fabs(m[col][col]);
      for (int r = col+1; r < 4; ++r) { double v = fabs(m[r][col]); if (v > best) { best = v; piv = r; } }
      if (piv != col) for (int c = 0; c < 8; ++c) { double tt = m[col][c]; m[col][c] = m[piv][c]; m[piv][c] = tt; }
      double pv = m[col][col];
      for (int c = 0; c < 8; ++c) m[col][c] /= pv;
      for (int r = 0; r < 4; ++r) if (r != col) {
        double f = m[r][col];
        for (int c = 0; c < 8; ++c) m[r][c] -= f * m[col][c];
      }
    }
    for (int r = 0; r < 3; ++r)
      for (int c = 0; c < 4; ++c) {
        double s = 0.0;
        for (int k = 0; k < 4; ++k) s += m[r][4+k] * (double)posses[k*4 + c];
        dsh[r*4 + c] = (float)s;
      }
  }
  __syncthreads();
  int j = blockIdx.x*256 + threadIdx.x;
  if (j >= NSV) return;
  float d[12];
  #pragma unroll
  for (int q = 0; q < 12; ++q) d[q] = dsh[q];
  float x = surc[j*3+0], y = surc[j*3+1], z = surc[j*3+2];
  float ax = ((x*d[0] + y*d[1]) + z*d[2]) + d[3];
  float ay = ((x*d[4] + y*d[5]) + z*d[6]) + d[7];
  float az = ((x*d[8] + y*d[9]) + z*d[10]) + d[11];
  const float4* f2 = (const float4*)(surf  + (size_t)j*CF);
  const float4* f1 = (const float4*)(meanf + (size_t)j*CF);
  float s2 = 0.f, s1 = 0.f;
  #pragma unroll
  for (int kq = 0; kq < 24; ++kq) {
    float4 v = f2[kq]; s2 += v.x*v.x; s2 += v.y*v.y; s2 += v.z*v.z; s2 += v.w*v.w;
  }
  #pragma unroll
  for (int kq = 0; kq < 24; ++kq) {
    float4 v = f1[kq]; s1 += v.x*v.x; s1 += v.y*v.y; s1 += v.z*v.z; s1 += v.w*v.w;
  }
  float4 cvv; cvv.x = 1.0f/sqrtf(s2); cvv.y = ax; cvv.z = ay; cvv.w = az;
  ((float4*)(wsb + OFF_CV4))[j] = cvv;
  float4 rvv; rvv.x = 1.0f/sqrtf(s1); rvv.y = ori[j*3+0]; rvv.z = ori[j*3+1]; rvv.w = ori[j*3+2];
  ((float4*)(wsb + OFF_RV4))[j] = rvv;
}

// 3-way bf16 split of PRE-SCALED features (A x 48.09/|a|, B x 1/|b|),
// written in MFMA-fragment-packed order (see layout comment above).
__global__ void k_split(const float* __restrict__ meanf, const float* __restrict__ surf,
                        char* __restrict__ wsb) {
  const int NT = NSV*CF/4;
  int idx = blockIdx.x*256 + threadIdx.x;
  if (idx >= 2*NT) return;
  int m = idx >= NT;
  int e4 = idx - (m ? NT : 0);
  int base4 = e4 * 4;
  int row = base4 / CF;
  int k0  = base4 - row*CF;          // 0,4,...,92
  const float* src = m ? surf : meanf;
  float scale;
  if (m) scale = ((const float4*)(wsb + OFF_CV4))[row].x;
  else   scale = ((const float4*)(wsb + OFF_RV4))[row].x * C48;
  unsigned short* d0 = (unsigned short*)(wsb + (m ? OFF_B0 : OFF_A0));
  unsigned short* d1 = (unsigned short*)(wsb + (m ? OFF_B1 : OFF_A1));
  unsigned short* d2 = (unsigned short*)(wsb + (m ? OFF_B2 : OFF_A2));
  float4 v = *(const float4*)(src + base4);
  float xs[4] = {v.x*scale, v.y*scale, v.z*scale, v.w*scale};
  unsigned short h0[4], h1[4], h2[4];
  #pragma unroll
  for (int c = 0; c < 4; ++c) {
    float x = xs[c];
    unsigned short a0 = bfr(x);  float r1 = x - bff(a0);
    unsigned short a1 = bfr(r1); float r2 = r1 - bff(a1);
    h0[c] = a0; h1[c] = a1; h2[c] = bfr(r2);
  }
  // fragment-packed destination (in ushort units):
  int g   = row >> 5;
  int l31 = row & 31;
  int kc  = k0 >> 4;
  int hi  = (k0 >> 3) & 1;
  int e8  = k0 & 7;                  // 0 or 4
  int offu = ((g*6 + kc) << 9) + (((hi << 5) | l31) << 3) + e8;
  *(ushort4*)(d0 + offu) = make_ushort4(h0[0], h0[1], h0[2], h0[3]);
  *(ushort4*)(d1 + offu) = make_ushort4(h1[0], h1[1], h1[2], h1[3]);
  *(ushort4*)(d2 + offu) = make_ushort4(h2[0], h2[1], h2[2], h2[3]);
}

// Heavy GEMM pass: 128x128 tile, 4 waves (2x2), wave tile 64x64 via 2x2 mfma_32x32x16_bf16.
// NO LDS staging, NO main-loop barriers: fragments loaded directly from L2-resident
// fragment-packed splits (fully coalesced: 64 lanes x 16B contiguous per load),
// register double-buffered.  PASS 1: rowsums.  PASS 2: per-column argmax of K*b.
template<int PASS>
__global__ __launch_bounds__(256, 2)
void k_gemm(char* __restrict__ wsb) {
  const float4* RV  = (const float4*)(wsb + OFF_RV4);
  const float4* CVC = (const float4*)(wsb + OFF_CV4);
  float* PROW = (float*)(wsb + OFF_PROW);
  unsigned long long* SME = (unsigned long long*)(wsb + OFF_SMENC);

  __shared__ unsigned long long redbuf[2][128];

  int t = threadIdx.x, lane = t & 63, wid = t >> 6;
  int wr = wid >> 1, wc = wid & 1, l31 = lane & 31, hi = lane >> 5;
  // 2D XCD chunking: XCD (xr,xc) owns 16 bi x 32 bj -> L2-resident panels
  int flat = blockIdx.y*64 + blockIdx.x;
  int xcd = flat & 7, q = flat >> 3;
  int xr = xcd >> 1, xc = xcd & 1;
  int bi = xr*16 + (q & 15), bj = xc*32 + (q >> 4);
  int I0 = bi*128, J0 = bj*128;

  // fragment base pointers: split s, sub-tile ti -> group (I0>>5) + wr*2 + ti
  const char* pA[3][2];
  const char* pB[3][2];
  {
    int gA = (I0 >> 5) + wr*2;
    int gB = (J0 >> 5) + wc*2;
    unsigned offs[3] = {OFF_A0, OFF_A1, OFF_A2};
    unsigned offsB[3] = {OFF_B0, OFF_B1, OFF_B2};
    #pragma unroll
    for (int s = 0; s < 3; ++s)
      #pragma unroll
      for (int ti = 0; ti < 2; ++ti) {
        pA[s][ti] = wsb + offs[s]  + (((gA + ti)*6) << 10) + lane*16;
        pB[s][ti] = wsb + offsB[s] + (((gB + ti)*6) << 10) + lane*16;
      }
  }

  floatx16 acc[2][2];
  #pragma unroll
  for (int ti = 0; ti < 2; ++ti)
    #pragma unroll
    for (int tj = 0; tj < 2; ++tj)
      #pragma unroll
      for (int e = 0; e < 16; ++e) acc[ti][tj][e] = 0.f;

  short8 fa[3][2], fb[3][2];
  #pragma unroll
  for (int s = 0; s < 3; ++s)
    #pragma unroll
    for (int ti = 0; ti < 2; ++ti) {
      fa[s][ti] = *(const short8*)(pA[s][ti]);
      fb[s][ti] = *(const short8*)(pB[s][ti]);
    }

  #pragma unroll
  for (int kc = 0; kc < 6; ++kc) {
    short8 na[3][2], nb[3][2];
    if (kc < 5) {
      #pragma unroll
      for (int s = 0; s < 3; ++s)
        #pragma unroll
        for (int ti = 0; ti < 2; ++ti) {
          na[s][ti] = *(const short8*)(pA[s][ti] + (kc+1)*1024);
          nb[s][ti] = *(const short8*)(pB[s][ti] + (kc+1)*1024);
        }
    }
    #pragma unroll
    for (int ti = 0; ti < 2; ++ti)
      #pragma unroll
      for (int tj = 0; tj < 2; ++tj) {
        acc[ti][tj] = __builtin_amdgcn_mfma_f32_32x32x16_bf16(fa[0][ti], fb[0][tj], acc[ti][tj], 0, 0, 0);
        acc[ti][tj] = __builtin_amdgcn_mfma_f32_32x32x16_bf16(fa[0][ti], fb[1][tj], acc[ti][tj], 0, 0, 0);
        acc[ti][tj] = __builtin_amdgcn_mfma_f32_32x32x16_bf16(fa[1][ti], fb[0][tj], acc[ti][tj], 0, 0, 0);
        acc[ti][tj] = __builtin_amdgcn_mfma_f32_32x32x16_bf16(fa[1][ti], fb[1][tj], acc[ti][tj], 0, 0, 0);
        acc[ti][tj] = __builtin_amdgcn_mfma_f32_32x32x16_bf16(fa[0][ti], fb[2][tj], acc[ti][tj], 0, 0, 0);
        acc[ti][tj] = __builtin_amdgcn_mfma_f32_32x32x16_bf16(fa[2][ti], fb[0][tj], acc[ti][tj], 0, 0, 0);
      }
    if (kc < 5) {
      #pragma unroll
      for (int s = 0; s < 3; ++s)
        #pragma unroll
        for (int ti = 0; ti < 2; ++ti) { fa[s][ti] = na[s][ti]; fb[s][ti] = nb[s][ti]; }
    }
  }

  // ---- epilogue ----
  float4 cv[2];
  #pragma unroll
  for (int tj = 0; tj < 2; ++tj) cv[tj] = CVC[J0 + wc*64 + tj*32 + l31];

  if (PASS == 1) {
    float* rowred = (float*)redbuf;   // [2][128] floats
    #pragma unroll
    for (int ti = 0; ti < 2; ++ti) {
      #pragma unroll
      for (int r = 0; r < 16; ++r) {
        int lr = wr*64 + ti*32 + (r & 3) + 8*(r >> 2) + 4*hi;
        int row = I0 + lr;
        float4 rv = RV[row];
        float rowp = 0.f;
        #pragma unroll
        for (int tj = 0; tj < 2; ++tj) {
          float dotv = acc[ti][tj][r];                  // = 48.09 * cos
          float dx = rv.y - cv[tj].y, dy = rv.z - cv[tj].z, dz = rv.w - cv[tj].w;
          float s3 = fmaf(dz, dz, fmaf(dy, dy, dx*dx));
          float ev = fexp2(s3 * CEV);                   // exp(-2*s3)
          float kv = fexp2(fmaf(ev, C48, dotv - C96));
          kv = (s3 < 25.0f) ? kv : 0.0f;
          rowp += kv;
        }
        rowp += __shfl_xor(rowp, 1);
        rowp += __shfl_xor(rowp, 2);
        rowp += __shfl_xor(rowp, 4);
        rowp += __shfl_xor(rowp, 8);
        rowp += __shfl_xor(rowp, 16);
        if (l31 == 0) rowred[wc*128 + lr] = rowp;
      }
    }
    __syncthreads();
    if (t < 128) PROW[(size_t)(I0 + t)*64 + bj] = rowred[t] + rowred[128 + t];
  } else {
    unsigned long long benc[2] = {0ull, 0ull};
    #pragma unroll
    for (int ti = 0; ti < 2; ++ti) {
      #pragma unroll
      for (int r = 0; r < 16; ++r) {
        int lr = wr*64 + ti*32 + (r & 3) + 8*(r >> 2) + 4*hi;
        int row = I0 + lr;
        float4 rv = RV[row];                            // rv.x = b_i
        unsigned rinv = 0xFFFFFFFFu - (unsigned)row;
        #pragma unroll
        for (int tj = 0; tj < 2; ++tj) {
          float dotv = acc[ti][tj][r];
          float dx = rv.y - cv[tj].y, dy = rv.z - cv[tj].z, dz = rv.w - cv[tj].w;
          float s3 = fmaf(dz, dz, fmaf(dy, dy, dx*dx));
          float ev = fexp2(s3 * CEV);
          float kv = fexp2(fmaf(ev, C48, dotv - C96));
          kv = (s3 < 25.0f) ? kv : 0.0f;
          float val = kv * rv.x;
          unsigned long long e = ((unsigned long long)__float_as_uint(val) << 32)
                               | (unsigned long long)rinv;
          benc[tj] = (e > benc[tj]) ? e : benc[tj];
        }
      }
    }
    #pragma unroll
    for (int tj = 0; tj < 2; ++tj) {
      unsigned long long o = __shfl_xor(benc[tj], 32);
      if (o > benc[tj]) benc[tj] = o;
      if (hi == 0) redbuf[wr][wc*64 + tj*32 + l31] = benc[tj];
    }
    __syncthreads();
    if (t < 128) {
      unsigned long long e0 = redbuf[0][t], e1 = redbuf[1][t];
      atomicMax(SME + (J0 + t), e0 > e1 ? e0 : e1);
    }
  }
}

// reduce partials -> b_i into RV4.x; init winner/flag/smenc
__global__ void k_bvec(char* __restrict__ wsb) {
  int i = blockIdx.x*256 + threadIdx.x;
  if (i >= NSV) return;
  const float* p = (const float*)(wsb + OFF_PROW) + (size_t)i*64;
  float s = 0.f;
  #pragma unroll
  for (int q = 0; q < 64; ++q) s += p[q];
  float b = 0x1p-13f / (s * 0x1p-13f + 1e-16f);
  ((float*)(wsb + OFF_RV4))[(size_t)i*4] = b;
  ((int*)(wsb + OFF_WIN))[i] = -1;
  ((unsigned long long*)(wsb + OFF_SMENC))[i] = 0ull;
  if (i == 0) *((int*)(wsb + OFF_FLAG)) = 0;
}

__global__ void k_softmax(const float* __restrict__ svp, float* __restrict__ out) {
  int i = blockIdx.x*256 + threadIdx.x;
  if (i >= NSV) return;
  const float* x = svp + (size_t)i*NCLS;
  float mx = x[0];
  for (int c = 1; c < NCLS; ++c) mx = fmaxf(mx, x[c]);
  float e[NCLS]; float s = 0.f;
  for (int c = 0; c < NCLS; ++c) { e[c] = expf(x[c] - mx); s += e[c]; }
  float* p = out + O_PROB + (size_t)i*NCLS;
  for (int c = 0; c < NCLS; ++c) p[c] = e[c]/s;
}

__global__ void k_conf(const int* __restrict__ gt, char* __restrict__ wsb, float* __restrict__ out) {
  int j = blockIdx.x*256 + threadIdx.x;
  if (j >= MSV) return;
  unsigned long long enc = ((const unsigned long long*)(wsb + OFF_SMENC))[j];
  int sm = (int)(0xFFFFFFFFu - (unsigned)(enc & 0xFFFFFFFFull));
  ((int*)(wsb + OFF_SMIDX))[j] = sm;
  out[O_SM + j] = (float)sm;
  float c = out[O_PROB + (size_t)sm*NCLS + gt[j]];
  ((float*)(wsb + OFF_CONF))[j] = c;
  unsigned long long m = __ballot(c > 0.1f);
  if ((threadIdx.x & 63) == 0 && m) atomicOr((int*)(wsb + OFF_FLAG), 1);
}

__global__ void k_winner(char* __restrict__ wsb) {
  int j = blockIdx.x*256 + threadIdx.x;
  if (j >= MSV) return;
  float c = ((const float*)(wsb + OFF_CONF))[j];
  int f = *((const int*)(wsb + OFF_FLAG));
  bool tm = f ? (c > 0.1f) : (c > 0.0f);
  if (tm) atomicMax(((int*)(wsb + OFF_WIN)) + ((const int*)(wsb + OFF_SMIDX))[j], j);
}

__global__ void k_final(const int* __restrict__ gt, float* __restrict__ out, const char* __restrict__ wsb) {
  int i = blockIdx.x*256 + threadIdx.x;
  if (i >= NSV) return;
  int w = ((const int*)(wsb + OFF_WIN))[i];
  float* row = out + O_PROB + (size_t)i*NCLS;
  if (w >= 0) {
    int g = gt[w];
    for (int c = 0; c < NCLS; ++c) row[c] = (c == g) ? 1.f : 0.f;
  }
  out[O_TRUST + i] = (w >= 0) ? 1.f : 0.f;
  float mx = row[0]; int pi = 0;
  for (int c = 1; c < NCLS; ++c) { float v = row[c]; if (v > mx) { mx = v; pi = c; } }
  out[O_PRE + i] = (float)pi;
}

extern "C" void kernel_launch(void* const* d_in, const int* in_sizes, int n_in,
                              void* d_out, int out_size, void* d_ws, size_t ws_size,
                              hipStream_t stream) {
  const float* surf  = (const float*)d_in[0];
  const float* surc  = (const float*)d_in[1];
  const int*   gt    = (const int*)d_in[2];
  const float* svp   = (const float*)d_in[3];
  const float* meanf = (const float*)d_in[4];
  const float* ori   = (const float*)d_in[5];
  const float* poss  = (const float*)d_in[6];
  float* out = (float*)d_out;
  char* wsb = (char*)d_ws;

  k_prep<<<NSV/256, 256, 0, stream>>>(surf, surc, meanf, ori, poss, wsb);
  k_split<<<1536, 256, 0, stream>>>(meanf, surf, wsb);
  k_gemm<1><<<dim3(64, 64), 256, 0, stream>>>(wsb);
  k_bvec<<<NSV/256, 256, 0, stream>>>(wsb);
  k_gemm<2><<<dim3(64, 64), 256, 0, stream>>>(wsb);
  k_softmax<<<NSV/256, 256, 0, stream>>>(svp, out);
  k_conf<<<MSV/256, 256, 0, stream>>>(gt, wsb, out);
  k_winner<<<MSV/256, 256, 0, stream>>>(wsb);
  k_final<<<NSV/256, 256, 0, stream>>>(gt, out, wsb);
}